// Round 5
// baseline (978.237 us; speedup 1.0000x reference)
//
#include <hip/hip_runtime.h>

#define INPUT_SIZE 32768
#define NUM_COLS   4096
#define NUM_ACTIVE 82
#define ROWS_PER_BLOCK 8
#define NF4 (INPUT_SIZE / 4)   // 8192 float4 per row

typedef float v4f __attribute__((ext_vector_type(4)));

__device__ __forceinline__ float dot4(v4f a, v4f b) {
    return a.x * b.x + a.y * b.y + a.z * b.z + a.w * b.w;
}

// Kernel A (measurement round: launched 5x to expose its true duration as
// dur_us delta; writes are idempotent exact integers so repeats are safe).
__global__ __launch_bounds__(256) void matvec_boost_kernel(
    const float* __restrict__ conn, const float* __restrict__ input,
    const float* __restrict__ boost, float* __restrict__ overlap)
{
    const int r0 = blockIdx.x * ROWS_PER_BLOCK;
    const int t  = threadIdx.x;
    const v4f* in4 = (const v4f*)input;
    const v4f* row[ROWS_PER_BLOCK];
    #pragma unroll
    for (int r = 0; r < ROWS_PER_BLOCK; ++r)
        row[r] = (const v4f*)(conn + (size_t)(r0 + r) * INPUT_SIZE);

    float acc[ROWS_PER_BLOCK];
    #pragma unroll
    for (int r = 0; r < ROWS_PER_BLOCK; ++r) acc[r] = 0.f;

    for (int k = t; k < NF4; k += 512) {
        const int k2 = k + 256;
        v4f b0 = in4[k];
        v4f b1 = in4[k2];
        v4f a0[ROWS_PER_BLOCK], a1[ROWS_PER_BLOCK];
        #pragma unroll
        for (int r = 0; r < ROWS_PER_BLOCK; ++r) {
            a0[r] = __builtin_nontemporal_load(&row[r][k]);
            a1[r] = __builtin_nontemporal_load(&row[r][k2]);
        }
        #pragma unroll
        for (int r = 0; r < ROWS_PER_BLOCK; ++r)
            acc[r] += dot4(a0[r], b0) + dot4(a1[r], b1);
    }

    #pragma unroll
    for (int r = 0; r < ROWS_PER_BLOCK; ++r) {
        float a = acc[r];
        #pragma unroll
        for (int off = 32; off > 0; off >>= 1)
            a += __shfl_down(a, off, 64);
        acc[r] = a;
    }

    __shared__ float part[4][ROWS_PER_BLOCK];
    const int wave = t >> 6;
    if ((t & 63) == 0) {
        #pragma unroll
        for (int r = 0; r < ROWS_PER_BLOCK; ++r) part[wave][r] = acc[r];
    }
    __syncthreads();
    if (t < ROWS_PER_BLOCK) {
        float tot = part[0][t] + part[1][t] + part[2][t] + part[3][t];
        overlap[r0 + t] = tot * boost[r0 + t];
    }
}

// Kernel B: exact stable top-k membership. One wave per column.
// rank(c) = #{ j : v_j > v_c  OR  (v_j == v_c AND j < c) } — matches
// jax.lax.top_k's lowest-index tie-break. active iff rank < 82.
__global__ __launch_bounds__(64) void topk_mask_kernel(
    const float* __restrict__ vals, float* __restrict__ out)
{
    const int c = blockIdx.x;
    const int lane = threadIdx.x;
    const float v = vals[c];
    const float4* v4 = (const float4*)vals;

    int cnt = 0;
    #pragma unroll
    for (int k = 0; k < NUM_COLS / 4 / 64; ++k) {   // 16 iterations
        const int i4 = lane + 64 * k;
        float4 b = v4[i4];
        const int j = i4 * 4;
        cnt += (b.x > v) || (b.x == v && (j + 0) < c);
        cnt += (b.y > v) || (b.y == v && (j + 1) < c);
        cnt += (b.z > v) || (b.z == v && (j + 2) < c);
        cnt += (b.w > v) || (b.w == v && (j + 3) < c);
    }
    #pragma unroll
    for (int off = 32; off > 0; off >>= 1)
        cnt += __shfl_down(cnt, off, 64);

    if (lane == 0) {
        const bool act = cnt < NUM_ACTIVE;
        out[c] = act ? 1.0f : 0.0f;
        out[NUM_COLS + c] = act ? v : 0.0f;
    }
}

extern "C" void kernel_launch(void* const* d_in, const int* in_sizes, int n_in,
                              void* d_out, int out_size, void* d_ws, size_t ws_size,
                              hipStream_t stream) {
    const float* input = (const float*)d_in[0];   // [32768]
    const float* conn  = (const float*)d_in[1];   // [4096, 32768]
    const float* boost = (const float*)d_in[2];   // [4096]
    float* out = (float*)d_out;                   // [8192]: mask then masked-boosted
    float* ov  = (float*)d_ws;                    // [4096] boosted overlaps

    // MEASUREMENT: 5 identical idempotent launches; T_matvec = (dur-652)/4.
    for (int i = 0; i < 5; ++i)
        matvec_boost_kernel<<<NUM_COLS / ROWS_PER_BLOCK, 256, 0, stream>>>(conn, input, boost, ov);
    topk_mask_kernel<<<NUM_COLS, 64, 0, stream>>>(ov, out);
}

// Round 6
// 684.304 us; speedup vs baseline: 1.4295x; 1.4295x over previous
//
#include <hip/hip_runtime.h>

#define INPUT_SIZE 32768
#define NUM_COLS   4096
#define NUM_ACTIVE 82
#define ROWS_PER_BLOCK 8

// ---------------------------------------------------------------------------
// Sparse formulation: input is ~5% dense; overlap[c] = sum over on-bits i of
// conn[c,i]*input[i]. All products are 0/1 and sums are exact fp32 integers
// (< 2^24), so ANY summation order is bit-exact vs the dense numpy reference
// -> top-k tie-breaks are unaffected.
// ---------------------------------------------------------------------------

__global__ void zero_counter_kernel(int* __restrict__ cnt) {
    if (threadIdx.x == 0) *cnt = 0;
}

// Wave-ballot stream compaction of nonzero input positions. Chunk order is
// scrambled by the atomic, but within a 64-element chunk indices stay
// ascending (good gather locality). Exactness does not depend on order.
__global__ __launch_bounds__(256) void compact_kernel(
    const float* __restrict__ input, int* __restrict__ nnz,
    int* __restrict__ idx, float* __restrict__ val)
{
    const int gid  = blockIdx.x * 256 + threadIdx.x;
    const int lane = threadIdx.x & 63;
    const float v  = input[gid];
    const unsigned long long m = __ballot(v != 0.0f);
    const int nactive = __popcll(m);
    const int myoff   = __popcll(m & ((1ull << lane) - 1ull));
    int base = 0;
    if (lane == 0 && nactive) base = atomicAdd(nnz, nactive);
    base = __shfl(base, 0, 64);
    if (v != 0.0f) { idx[base + myoff] = gid; val[base + myoff] = v; }
}

// Gather matvec: 8 rows/block, 256 threads, grid=512. Each thread walks the
// nnz list strided; idx/val (~13 KB) are L1-resident after first pass. Only
// cache lines containing on-bits are fetched from HBM.
__global__ __launch_bounds__(256) void gather_matvec_kernel(
    const float* __restrict__ conn, const int* __restrict__ nnzp,
    const int* __restrict__ idx, const float* __restrict__ val,
    const float* __restrict__ boost, float* __restrict__ overlap)
{
    const int r0 = blockIdx.x * ROWS_PER_BLOCK;
    const int t  = threadIdx.x;
    const int nnz = *nnzp;

    const float* row[ROWS_PER_BLOCK];
    #pragma unroll
    for (int r = 0; r < ROWS_PER_BLOCK; ++r)
        row[r] = conn + (size_t)(r0 + r) * INPUT_SIZE;

    float acc[ROWS_PER_BLOCK];
    #pragma unroll
    for (int r = 0; r < ROWS_PER_BLOCK; ++r) acc[r] = 0.f;

    for (int j = t; j < nnz; j += 256) {
        const int   ii = idx[j];
        const float v  = val[j];
        #pragma unroll
        for (int r = 0; r < ROWS_PER_BLOCK; ++r)
            acc[r] += row[r][ii] * v;
    }

    // wave64 shuffle reduce each accumulator
    #pragma unroll
    for (int r = 0; r < ROWS_PER_BLOCK; ++r) {
        float a = acc[r];
        #pragma unroll
        for (int off = 32; off > 0; off >>= 1)
            a += __shfl_down(a, off, 64);
        acc[r] = a;
    }

    __shared__ float part[4][ROWS_PER_BLOCK];
    const int wave = t >> 6;
    if ((t & 63) == 0) {
        #pragma unroll
        for (int r = 0; r < ROWS_PER_BLOCK; ++r) part[wave][r] = acc[r];
    }
    __syncthreads();
    if (t < ROWS_PER_BLOCK) {
        float tot = part[0][t] + part[1][t] + part[2][t] + part[3][t];
        overlap[r0 + t] = tot * boost[r0 + t];
    }
}

// Exact stable top-k membership. One wave per column.
// rank(c) = #{ j : v_j > v_c  OR  (v_j == v_c AND j < c) } — matches
// jax.lax.top_k's lowest-index tie-break. active iff rank < 82.
__global__ __launch_bounds__(64) void topk_mask_kernel(
    const float* __restrict__ vals, float* __restrict__ out)
{
    const int c = blockIdx.x;
    const int lane = threadIdx.x;
    const float v = vals[c];
    const float4* v4 = (const float4*)vals;

    int cnt = 0;
    #pragma unroll
    for (int k = 0; k < NUM_COLS / 4 / 64; ++k) {   // 16 iterations
        const int i4 = lane + 64 * k;
        float4 b = v4[i4];
        const int j = i4 * 4;
        cnt += (b.x > v) || (b.x == v && (j + 0) < c);
        cnt += (b.y > v) || (b.y == v && (j + 1) < c);
        cnt += (b.z > v) || (b.z == v && (j + 2) < c);
        cnt += (b.w > v) || (b.w == v && (j + 3) < c);
    }
    #pragma unroll
    for (int off = 32; off > 0; off >>= 1)
        cnt += __shfl_down(cnt, off, 64);

    if (lane == 0) {
        const bool act = cnt < NUM_ACTIVE;
        out[c] = act ? 1.0f : 0.0f;
        out[NUM_COLS + c] = act ? v : 0.0f;
    }
}

extern "C" void kernel_launch(void* const* d_in, const int* in_sizes, int n_in,
                              void* d_out, int out_size, void* d_ws, size_t ws_size,
                              hipStream_t stream) {
    const float* input = (const float*)d_in[0];   // [32768]
    const float* conn  = (const float*)d_in[1];   // [4096, 32768]
    const float* boost = (const float*)d_in[2];   // [4096]
    float* out = (float*)d_out;                   // [8192]: mask then masked-boosted

    // ws layout: ov[4096] f32 | nnz counter (aligned) | idx[32768] i32 | val[32768] f32
    float* ov  = (float*)d_ws;
    int*   nnz = (int*)(ov + NUM_COLS);
    int*   idx = nnz + 64;                        // 256B-align the list
    float* val = (float*)(idx + INPUT_SIZE);

    zero_counter_kernel<<<1, 64, 0, stream>>>(nnz);
    compact_kernel<<<INPUT_SIZE / 256, 256, 0, stream>>>(input, nnz, idx, val);
    gather_matvec_kernel<<<NUM_COLS / ROWS_PER_BLOCK, 256, 0, stream>>>(conn, nnz, idx, val, boost, ov);
    topk_mask_kernel<<<NUM_COLS, 64, 0, stream>>>(ov, out);
}

// Round 7
// 664.578 us; speedup vs baseline: 1.4720x; 1.0297x over previous
//
#include <hip/hip_runtime.h>

#define INPUT_SIZE 32768
#define NUM_COLS   4096
#define NUM_ACTIVE 82
#define ROWS_PER_BLOCK 8
#define NF4 (INPUT_SIZE / 4)   // 8192 float4 per row

typedef float v4f __attribute__((ext_vector_type(4)));

__device__ __forceinline__ float dot4(v4f a, v4f b) {
    return a.x * b.x + a.y * b.y + a.z * b.z + a.w * b.w;
}

// Kernel A: boosted overlap = (connections @ input) * boost.
// ROOFLINE CONFIG (measured R5): 81.4 us = 6.29 TB/s read = 99.7% of
// achievable HBM read BW. 8 rows/block, 256 threads, grid=512; conn streamed
// once with nontemporal loads (R2 vs R3: nt worth ~27 us); input float4
// amortized over 8 rows. Sums of 0/1 products are exact fp32 integers ->
// bit-exact vs numpy in any summation order.
// Rejected alternatives (measured): occupancy 32 waves/CU (R3: neutral-to-worse),
// sparse gather over on-bits (R6: +29 us, TA request-rate-bound at 5% density).
__global__ __launch_bounds__(256) void matvec_boost_kernel(
    const float* __restrict__ conn, const float* __restrict__ input,
    const float* __restrict__ boost, float* __restrict__ overlap)
{
    const int r0 = blockIdx.x * ROWS_PER_BLOCK;
    const int t  = threadIdx.x;
    const v4f* in4 = (const v4f*)input;
    const v4f* row[ROWS_PER_BLOCK];
    #pragma unroll
    for (int r = 0; r < ROWS_PER_BLOCK; ++r)
        row[r] = (const v4f*)(conn + (size_t)(r0 + r) * INPUT_SIZE);

    float acc[ROWS_PER_BLOCK];
    #pragma unroll
    for (int r = 0; r < ROWS_PER_BLOCK; ++r) acc[r] = 0.f;

    for (int k = t; k < NF4; k += 512) {
        const int k2 = k + 256;
        v4f b0 = in4[k];
        v4f b1 = in4[k2];
        v4f a0[ROWS_PER_BLOCK], a1[ROWS_PER_BLOCK];
        #pragma unroll
        for (int r = 0; r < ROWS_PER_BLOCK; ++r) {
            a0[r] = __builtin_nontemporal_load(&row[r][k]);
            a1[r] = __builtin_nontemporal_load(&row[r][k2]);
        }
        #pragma unroll
        for (int r = 0; r < ROWS_PER_BLOCK; ++r)
            acc[r] += dot4(a0[r], b0) + dot4(a1[r], b1);
    }

    // wave64 shuffle reduce each accumulator
    #pragma unroll
    for (int r = 0; r < ROWS_PER_BLOCK; ++r) {
        float a = acc[r];
        #pragma unroll
        for (int off = 32; off > 0; off >>= 1)
            a += __shfl_down(a, off, 64);
        acc[r] = a;
    }

    __shared__ float part[4][ROWS_PER_BLOCK];
    const int wave = t >> 6;
    if ((t & 63) == 0) {
        #pragma unroll
        for (int r = 0; r < ROWS_PER_BLOCK; ++r) part[wave][r] = acc[r];
    }
    __syncthreads();
    if (t < ROWS_PER_BLOCK) {
        float tot = part[0][t] + part[1][t] + part[2][t] + part[3][t];
        overlap[r0 + t] = tot * boost[r0 + t];
    }
}

// Kernel B: exact stable top-k membership. One wave per column.
// rank(c) = #{ j : v_j > v_c  OR  (v_j == v_c AND j < c) } — matches
// jax.lax.top_k's lowest-index tie-break. active iff rank < 82.
__global__ __launch_bounds__(64) void topk_mask_kernel(
    const float* __restrict__ vals, float* __restrict__ out)
{
    const int c = blockIdx.x;
    const int lane = threadIdx.x;
    const float v = vals[c];
    const float4* v4 = (const float4*)vals;

    int cnt = 0;
    #pragma unroll
    for (int k = 0; k < NUM_COLS / 4 / 64; ++k) {   // 16 iterations
        const int i4 = lane + 64 * k;
        float4 b = v4[i4];
        const int j = i4 * 4;
        cnt += (b.x > v) || (b.x == v && (j + 0) < c);
        cnt += (b.y > v) || (b.y == v && (j + 1) < c);
        cnt += (b.z > v) || (b.z == v && (j + 2) < c);
        cnt += (b.w > v) || (b.w == v && (j + 3) < c);
    }
    #pragma unroll
    for (int off = 32; off > 0; off >>= 1)
        cnt += __shfl_down(cnt, off, 64);

    if (lane == 0) {
        const bool act = cnt < NUM_ACTIVE;
        out[c] = act ? 1.0f : 0.0f;
        out[NUM_COLS + c] = act ? v : 0.0f;
    }
}

extern "C" void kernel_launch(void* const* d_in, const int* in_sizes, int n_in,
                              void* d_out, int out_size, void* d_ws, size_t ws_size,
                              hipStream_t stream) {
    const float* input = (const float*)d_in[0];   // [32768]
    const float* conn  = (const float*)d_in[1];   // [4096, 32768]
    const float* boost = (const float*)d_in[2];   // [4096]
    float* out = (float*)d_out;                   // [8192]: mask then masked-boosted
    float* ov  = (float*)d_ws;                    // [4096] boosted overlaps

    matvec_boost_kernel<<<NUM_COLS / ROWS_PER_BLOCK, 256, 0, stream>>>(conn, input, boost, ov);
    topk_mask_kernel<<<NUM_COLS, 64, 0, stream>>>(ov, out);
}